// Round 8
// baseline (152.365 us; speedup 1.0000x reference)
//
#include <hip/hip_runtime.h>

// Correlation via bf16 MFMA banded Gram.
// out[b, dyp*21+k, y, x] = (1/256) * sum_c in1[b,c,y,x] * in2[b,c,y+2(dyp-10), x+2(k-10)]
// Layouts (workspace): Ag/Bg[b*64+y][par*48+col][c] bf16, x = 2*col+par.
//
// R13: occupancy fix. Ledger across R5/R9 shows LDS 81,408 ran at 1 block/CU
// (2 waves/SIMD) -- 81,408*2 is within 1KB of the 163,840 limit and any runtime
// reservation tips it. New geometry: 6-wave blocks (384 thr = par x 3 slots),
// 1024 blocks (pg in [0,4), p in [0,2), dyp = pg*6 + p*3 + slot). LDS =
// Bsh 48K + scr[6] 24,192 = 72,384 B -> 2 blocks/CU with 19KB margin = 12
// waves/CU. XCD swizzle: chunk = xcd*2 + (i>>6); b = chunk>>2 (same b per XCD,
// working set Ag(b)+Bg(b) ~6.3MB). Inner loop unchanged from R11.

typedef short bf16x8 __attribute__((ext_vector_type(8)));
typedef float f32x4  __attribute__((ext_vector_type(4)));

#define PLANE 24576         // shorts per (b,y) plane: 96 rows * 256 c
#define ST    40            // prepass LDS row stride (shorts)

__device__ __forceinline__ short f2bf(float f) {
    union { float f; unsigned u; } x; x.f = f;
    const unsigned u = x.u;
    return (short)((u + 0x7fffu + ((u >> 16) & 1u)) >> 16);
}

// ---------- prepass: fp32 [b][c][y][x] -> bf16 [b*64+y][par*48+col][c] ----------
// block = (sel, b, ytile of 8, ctile of 32ch). Reads 3KB contiguous per channel.
__global__ __launch_bounds__(512)
void corr_prepass(const float* __restrict__ in1, const float* __restrict__ in2,
                  short* __restrict__ dstA, short* __restrict__ dstB) {
    const int bid = blockIdx.x;
    const int sel = bid >> 8;
    const int r   = bid & 255;
    const int b   = r >> 6;
    const int yt  = (r >> 3) & 7;
    const int ct  = r & 7;
    const int c0 = ct * 32, y0 = yt * 8;
    const float* src = sel ? in2 : in1;
    short* dst = sel ? dstB : dstA;

    __shared__ __align__(16) short T[768 * ST];   // [xx = yy*96+x][32c], 61.4 KB
    const int tid = threadIdx.x;

#pragma unroll
    for (int it = 0; it < 2; ++it) {
        const int d = it * 512 + tid;            // [0,1024), use d<768
        if (d < 768) {
            const int g = d / 192;               // channel octet 0..3
            const int f = d - g * 192;           // float4 index in 8y*96x chunk
            float4 v[8];
#pragma unroll
            for (int j = 0; j < 8; ++j) {
                const int c = c0 + g * 8 + j;
                v[j] = *(const float4*)(src + ((size_t)(b * 256 + c) * 64 + y0) * 96 + 4 * f);
            }
            bf16x8 w0, w1, w2, w3;
#pragma unroll
            for (int j = 0; j < 8; ++j) {
                w0[j] = f2bf(v[j].x); w1[j] = f2bf(v[j].y);
                w2[j] = f2bf(v[j].z); w3[j] = f2bf(v[j].w);
            }
            const int perm = ((g ^ (f & 3)) * 8);
            const int base = 4 * f * ST + perm;
            *(bf16x8*)&T[base]          = w0;
            *(bf16x8*)&T[base + ST]     = w1;
            *(bf16x8*)&T[base + 2*ST]   = w2;
            *(bf16x8*)&T[base + 3*ST]   = w3;
        }
    }
    __syncthreads();

#pragma unroll
    for (int it = 0; it < 6; ++it) {
        const int D  = it * 512 + tid;           // [0,3072)
        const int Rl = D >> 2, gp = D & 3;
        const int yy  = Rl / 96;
        const int rl  = Rl - yy * 96;
        const int par = rl / 48;
        const int col = rl - par * 48;
        const int x   = 2 * col + par;
        const int xx  = yy * 96 + x;
        const int perm = ((gp ^ ((xx >> 2) & 3)) * 8);
        const bf16x8 w = *(const bf16x8*)&T[xx * ST + perm];
        const size_t Rg = (size_t)(b * 64 + y0 + yy) * 96 + par * 48 + col;
        *(bf16x8*)(dst + Rg * 256 + c0 + gp * 8) = w;
    }
}

// ---------- main kernel: 384 threads = 6 waves = par(2) x slot(3) ----------
// Barrier-free rounds; wave-private scr; dyp = pg*6 + p*3 + slot, p in [0,2).
__global__ __launch_bounds__(384, 3)
void corr_mfma(const short* __restrict__ Ag, const short* __restrict__ Bg,
               float* __restrict__ out) {
    // XCD-chunked swizzle: 1024 blocks; each XCD gets 2 chunks of 64 with the
    // SAME b (working set = Ag(b)+Bg(b) ~6.3MB in its L2).
    const int hw   = blockIdx.x;                 // [0,1024)
    const int xcd  = hw & 7;
    const int i    = hw >> 3;                    // [0,128)
    const int chunk = xcd * 2 + (i >> 6);        // [0,16)
    const int b  = chunk >> 2;
    const int pg = chunk & 3;
    const int y2 = i & 63;
    const int by2 = b * 64 + y2;

    const int tid  = threadIdx.x;
    const int lane = tid & 63, w = tid >> 6;     // w in [0,6)
    const int par  = w & 1, slot = w >> 1;       // slot in [0,3)
    const int n    = lane & 15, q = lane >> 4;

    __shared__ __align__(16) short Bsh[96 * 256];    // 49152 B, XOR-swizzled rows
    __shared__ __align__(16) float scr[6][1008];     // 24192 B, per-wave, xe-major

    // stage B(b,y2) ONCE (swizzled: short_idx ^= (row&7)<<3  ==  byte ^= (row&7)<<4)
    {
        const short* src = Bg + (size_t)by2 * PLANE;
#pragma unroll
        for (int it = 0; it < 8; ++it) {
            const int j   = it * 384 + tid;      // [0,3072)
            const int row = j >> 5;
            const int ofs = (row * 256 + (j & 31) * 8) ^ ((row & 7) << 3);
            *(bf16x8*)&Bsh[ofs] = *(const bf16x8*)(src + j * 8);
        }
    }
    __syncthreads();                             // the ONLY block-wide barrier

    const bool v0 = (n >= 10), v3 = (n < 10);
    const int r0 = par * 48 + (v0 ? (n - 10) : 0);
    const int r1 = par * 48 + n + 6;
    const int r2 = par * 48 + n + 22;
    const int r3 = par * 48 + (v3 ? (n + 38) : 0);

    float* const sc = scr[w];

#pragma unroll
    for (int p = 0; p < 2; ++p) {
        const int dyp = pg * 6 + p * 3 + slot;
        const int y   = y2 + 20 - 2 * dyp;
        const bool live = (dyp < 21) && (y >= 0) && (y < 64);
        if (!live) continue;                     // wave-uniform

        f32x4 acc[9];
#pragma unroll
        for (int t2 = 0; t2 < 9; ++t2) acc[t2] = (f32x4)0.0f;

        // Per-lane A base; all 24 loads are static element offsets from it.
        // (Xi,ks) offset = Xi*4096 + ks*32 shorts.
        const short* Ap = Ag + ((size_t)(b * 64 + y) * 96 + par * 48) * 256
                        + n * 256 + q * 8;

        // 4-deep rotating ks-step buffers (all indices compile-time).
        bf16x8 a0[3], a1[3], a2[3], a3[3];
#define LOADA(buf, ks) \
        buf[0] = *(const bf16x8*)(Ap + 0 * 4096 + (ks) * 32); \
        buf[1] = *(const bf16x8*)(Ap + 1 * 4096 + (ks) * 32); \
        buf[2] = *(const bf16x8*)(Ap + 2 * 4096 + (ks) * 32);

        LOADA(a0, 0) LOADA(a1, 1) LOADA(a2, 2) LOADA(a3, 3)

#define STEP(ks, ab, PF) { \
        const int ko = (ks) * 32 + q * 8; \
        bf16x8 b0 = *(const bf16x8*)&Bsh[(r0 * 256 + ko) ^ ((r0 & 7) << 3)]; if (!v0) b0 = 0; \
        bf16x8 b1 = *(const bf16x8*)&Bsh[(r1 * 256 + ko) ^ ((r1 & 7) << 3)]; \
        bf16x8 b2 = *(const bf16x8*)&Bsh[(r2 * 256 + ko) ^ ((r2 & 7) << 3)]; \
        bf16x8 b3 = *(const bf16x8*)&Bsh[(r3 * 256 + ko) ^ ((r3 & 7) << 3)]; if (!v3) b3 = 0; \
        acc[0] = __builtin_amdgcn_mfma_f32_16x16x32_bf16(ab[0], b0, acc[0], 0, 0, 0); \
        acc[1] = __builtin_amdgcn_mfma_f32_16x16x32_bf16(ab[0], b1, acc[1], 0, 0, 0); \
        acc[2] = __builtin_amdgcn_mfma_f32_16x16x32_bf16(ab[0], b2, acc[2], 0, 0, 0); \
        acc[3] = __builtin_amdgcn_mfma_f32_16x16x32_bf16(ab[1], b1, acc[3], 0, 0, 0); \
        acc[4] = __builtin_amdgcn_mfma_f32_16x16x32_bf16(ab[1], b2, acc[4], 0, 0, 0); \
        acc[5] = __builtin_amdgcn_mfma_f32_16x16x32_bf16(ab[1], b3, acc[5], 0, 0, 0); \
        acc[6] = __builtin_amdgcn_mfma_f32_16x16x32_bf16(ab[2], b2, acc[6], 0, 0, 0); \
        acc[7] = __builtin_amdgcn_mfma_f32_16x16x32_bf16(ab[2], b3, acc[7], 0, 0, 0); \
        if (PF) { LOADA(ab, (ks) + 4) } \
    }
        // acc[8] = (X2,U4): all B cols OOB -> stays zero (real zero outputs)

        STEP(0, a0, 1) STEP(1, a1, 1) STEP(2, a2, 1) STEP(3, a3, 1)
        STEP(4, a0, 0) STEP(5, a1, 0) STEP(6, a2, 0) STEP(7, a3, 0)
#undef STEP
#undef LOADA

        // wave-private scatter: sc[xe*21 + k]  (xe-major: <=2-way bank aliasing)
        const int mb = q * 4;
#pragma unroll
        for (int t2 = 0; t2 < 9; ++t2) {
            const int Xi = (t2 < 3) ? 0 : (t2 < 6 ? 1 : 2);
            constexpr int UJ[9] = {0, 1, 2, 1, 2, 3, 2, 3, 4};
            const int ub = UJ[t2] * 16;
#pragma unroll
            for (int rr = 0; rr < 4; ++rr) {
                const int xe = Xi * 16 + mb + rr;
                const int k  = ub + n - xe;
                if ((unsigned)k < 21u)
                    sc[xe * 21 + k] = acc[t2][rr];
            }
        }

        // wave-private store: gather 16 values first (breaks read->store chain),
        // then 16 stores. k-major for x-locality; stride-2, par sibling fills
        // the other half of each line through L2.
        const size_t obase = ((size_t)(b * 441 + dyp * 21) * 64 + y) * 96 + par;
        float vals[16];
#pragma unroll
        for (int it = 0; it < 16; ++it) {
            const int e = it * 64 + lane;        // [0,1024), valid < 1008
            vals[it] = (e < 1008) ? sc[(e % 48) * 21 + (e / 48)] : 0.0f;
        }
#pragma unroll
        for (int it = 0; it < 16; ++it) {
            const int e = it * 64 + lane;
            if (e < 1008) {
                const int k  = e / 48;
                const int xe = e - k * 48;
                out[obase + (size_t)k * 6144 + 2 * xe] = vals[it] * (1.0f / 256.0f);
            }
        }
    }
}

extern "C" void kernel_launch(void* const* d_in, const int* in_sizes, int n_in,
                              void* d_out, int out_size, void* d_ws, size_t ws_size,
                              hipStream_t stream) {
    const float* in1 = (const float*)d_in[0];
    const float* in2 = (const float*)d_in[1];
    float* out = (float*)d_out;

    short* Ag = (short*)d_ws;                    // 256 planes * 24576 shorts = 12.58 MB
    short* Bg = Ag + (size_t)256 * PLANE;        // 12.58 MB

    corr_prepass<<<dim3(512), dim3(512), 0, stream>>>(in1, in2, Ag, Bg);
    corr_mfma<<<dim3(1024), dim3(384), 0, stream>>>(Ag, Bg, out);
}

// Round 9
// 134.067 us; speedup vs baseline: 1.1365x; 1.1365x over previous
//
#include <hip/hip_runtime.h>

// Correlation via bf16 MFMA banded Gram.
// out[b, dyp*21+k, y, x] = (1/256) * sum_c in1[b,c,y,x] * in2[b,c,y+2(dyp-10), x+2(k-10)]
// Layouts (workspace): Ag/Bg[b*64+y][par*48+col][c] bf16, x = 2*col+par.
//
// R15: par-split main blocks. Block = 512 thr = 8 waves, ALL the same par
// (slots 0..7), p in [0,3), dyp = p*8+slot. Bsh stages only the par half
// (48 rows, 24KB); scr[8] = 32.25KB; LDS = 56,832B -> 2 blocks/CU with 50KB
// margin (16 waves/CU = 4/SIMD, 2x R9's true residency). Grid stays 512 so
// each B half-plane is staged exactly once (fixes R13's +20MB refetch).
// A access is par-restricted -> per-XCD set = A(b,par)+B(b,par) = 3.15MB < 4MB
// L2 with chunk = par*4+b. Inner loop identical to R11.

typedef short bf16x8 __attribute__((ext_vector_type(8)));
typedef float f32x4  __attribute__((ext_vector_type(4)));

#define PLANE 24576         // shorts per (b,y) plane: 96 rows * 256 c
#define ST    40            // prepass LDS row stride (shorts)

__device__ __forceinline__ short f2bf(float f) {
    union { float f; unsigned u; } x; x.f = f;
    const unsigned u = x.u;
    return (short)((u + 0x7fffu + ((u >> 16) & 1u)) >> 16);
}

// ---------- prepass: fp32 [b][c][y][x] -> bf16 [b*64+y][par*48+col][c] ----------
// block = (sel, b, ytile of 8, ctile of 32ch). Reads 3KB contiguous per channel.
__global__ __launch_bounds__(512)
void corr_prepass(const float* __restrict__ in1, const float* __restrict__ in2,
                  short* __restrict__ dstA, short* __restrict__ dstB) {
    const int bid = blockIdx.x;
    const int sel = bid >> 8;
    const int r   = bid & 255;
    const int b   = r >> 6;
    const int yt  = (r >> 3) & 7;
    const int ct  = r & 7;
    const int c0 = ct * 32, y0 = yt * 8;
    const float* src = sel ? in2 : in1;
    short* dst = sel ? dstB : dstA;

    __shared__ __align__(16) short T[768 * ST];   // [xx = yy*96+x][32c], 61.4 KB
    const int tid = threadIdx.x;

#pragma unroll
    for (int it = 0; it < 2; ++it) {
        const int d = it * 512 + tid;            // [0,1024), use d<768
        if (d < 768) {
            const int g = d / 192;               // channel octet 0..3
            const int f = d - g * 192;           // float4 index in 8y*96x chunk
            float4 v[8];
#pragma unroll
            for (int j = 0; j < 8; ++j) {
                const int c = c0 + g * 8 + j;
                v[j] = *(const float4*)(src + ((size_t)(b * 256 + c) * 64 + y0) * 96 + 4 * f);
            }
            bf16x8 w0, w1, w2, w3;
#pragma unroll
            for (int j = 0; j < 8; ++j) {
                w0[j] = f2bf(v[j].x); w1[j] = f2bf(v[j].y);
                w2[j] = f2bf(v[j].z); w3[j] = f2bf(v[j].w);
            }
            const int perm = ((g ^ (f & 3)) * 8);
            const int base = 4 * f * ST + perm;
            *(bf16x8*)&T[base]          = w0;
            *(bf16x8*)&T[base + ST]     = w1;
            *(bf16x8*)&T[base + 2*ST]   = w2;
            *(bf16x8*)&T[base + 3*ST]   = w3;
        }
    }
    __syncthreads();

#pragma unroll
    for (int it = 0; it < 6; ++it) {
        const int D  = it * 512 + tid;           // [0,3072)
        const int Rl = D >> 2, gp = D & 3;
        const int yy  = Rl / 96;
        const int rl  = Rl - yy * 96;
        const int par = rl / 48;
        const int col = rl - par * 48;
        const int x   = 2 * col + par;
        const int xx  = yy * 96 + x;
        const int perm = ((gp ^ ((xx >> 2) & 3)) * 8);
        const bf16x8 w = *(const bf16x8*)&T[xx * ST + perm];
        const size_t Rg = (size_t)(b * 64 + y0 + yy) * 96 + par * 48 + col;
        *(bf16x8*)(dst + Rg * 256 + c0 + gp * 8) = w;
    }
}

// ---------- main kernel: 512 threads = 8 waves = 8 slots, single par ----------
// Barrier-free rounds; wave-private scr; dyp = p*8 + slot, p in [0,3).
__global__ __launch_bounds__(512, 2)
void corr_mfma(const short* __restrict__ Ag, const short* __restrict__ Bg,
               float* __restrict__ out) {
    // XCD-chunked swizzle: chunk of 64 blocks = (par,b); per-XCD working set
    // = A(b,par-half) + B(b,par-half) = 3.15MB (L2-resident).
    const int bhw = blockIdx.x;                  // [0,512)
    const int bid = ((bhw & 7) << 6) | (bhw >> 3);
    const int par = bid >> 8;
    const int b   = (bid >> 6) & 3;
    const int y2  = bid & 63;
    const int by2 = b * 64 + y2;

    const int tid  = threadIdx.x;
    const int lane = tid & 63, slot = tid >> 6;  // slot in [0,8)
    const int n    = lane & 15, q = lane >> 4;

    __shared__ __align__(16) short Bsh[48 * 256];    // 24576 B, XOR-swizzled rows
    __shared__ __align__(16) float scr[8][1008];     // 32256 B, per-wave, xe-major

    // stage B(b,y2) par-half ONCE (swizzle: short_idx ^= (row&7)<<3)
    {
        const short* src = Bg + (size_t)by2 * PLANE + par * 48 * 256;
#pragma unroll
        for (int it = 0; it < 3; ++it) {
            const int j   = it * 512 + tid;      // [0,1536)
            const int row = j >> 5;              // [0,48)
            const int ofs = (row * 256 + (j & 31) * 8) ^ ((row & 7) << 3);
            *(bf16x8*)&Bsh[ofs] = *(const bf16x8*)(src + j * 8);
        }
    }
    __syncthreads();                             // the ONLY block-wide barrier

    const bool v0 = (n >= 10), v3 = (n < 10);
    const int r0 = v0 ? (n - 10) : 0;
    const int r1 = n + 6;
    const int r2 = n + 22;
    const int r3 = v3 ? (n + 38) : 0;            // all in [0,48)

    float* const sc = scr[slot];

#pragma unroll
    for (int p = 0; p < 3; ++p) {
        const int dyp = p * 8 + slot;
        const int y   = y2 + 20 - 2 * dyp;
        const bool live = (dyp < 21) && (y >= 0) && (y < 64);
        if (!live) continue;                     // wave-uniform

        f32x4 acc[9];
#pragma unroll
        for (int t2 = 0; t2 < 9; ++t2) acc[t2] = (f32x4)0.0f;

        // Per-lane A base; all 24 loads are static element offsets from it.
        // (Xi,ks) offset = Xi*4096 + ks*32 shorts.
        const short* Ap = Ag + ((size_t)(b * 64 + y) * 96 + par * 48) * 256
                        + n * 256 + q * 8;

        // 4-deep rotating ks-step buffers (all indices compile-time).
        bf16x8 a0[3], a1[3], a2[3], a3[3];
#define LOADA(buf, ks) \
        buf[0] = *(const bf16x8*)(Ap + 0 * 4096 + (ks) * 32); \
        buf[1] = *(const bf16x8*)(Ap + 1 * 4096 + (ks) * 32); \
        buf[2] = *(const bf16x8*)(Ap + 2 * 4096 + (ks) * 32);

        LOADA(a0, 0) LOADA(a1, 1) LOADA(a2, 2) LOADA(a3, 3)

#define STEP(ks, ab, PF) { \
        const int ko = (ks) * 32 + q * 8; \
        bf16x8 b0 = *(const bf16x8*)&Bsh[(r0 * 256 + ko) ^ ((r0 & 7) << 3)]; if (!v0) b0 = 0; \
        bf16x8 b1 = *(const bf16x8*)&Bsh[(r1 * 256 + ko) ^ ((r1 & 7) << 3)]; \
        bf16x8 b2 = *(const bf16x8*)&Bsh[(r2 * 256 + ko) ^ ((r2 & 7) << 3)]; \
        bf16x8 b3 = *(const bf16x8*)&Bsh[(r3 * 256 + ko) ^ ((r3 & 7) << 3)]; if (!v3) b3 = 0; \
        acc[0] = __builtin_amdgcn_mfma_f32_16x16x32_bf16(ab[0], b0, acc[0], 0, 0, 0); \
        acc[1] = __builtin_amdgcn_mfma_f32_16x16x32_bf16(ab[0], b1, acc[1], 0, 0, 0); \
        acc[2] = __builtin_amdgcn_mfma_f32_16x16x32_bf16(ab[0], b2, acc[2], 0, 0, 0); \
        acc[3] = __builtin_amdgcn_mfma_f32_16x16x32_bf16(ab[1], b1, acc[3], 0, 0, 0); \
        acc[4] = __builtin_amdgcn_mfma_f32_16x16x32_bf16(ab[1], b2, acc[4], 0, 0, 0); \
        acc[5] = __builtin_amdgcn_mfma_f32_16x16x32_bf16(ab[1], b3, acc[5], 0, 0, 0); \
        acc[6] = __builtin_amdgcn_mfma_f32_16x16x32_bf16(ab[2], b2, acc[6], 0, 0, 0); \
        acc[7] = __builtin_amdgcn_mfma_f32_16x16x32_bf16(ab[2], b3, acc[7], 0, 0, 0); \
        if (PF) { LOADA(ab, (ks) + 4) } \
    }
        // acc[8] = (X2,U4): all B cols OOB -> stays zero (real zero outputs)

        STEP(0, a0, 1) STEP(1, a1, 1) STEP(2, a2, 1) STEP(3, a3, 1)
        STEP(4, a0, 0) STEP(5, a1, 0) STEP(6, a2, 0) STEP(7, a3, 0)
#undef STEP
#undef LOADA

        // wave-private scatter: sc[xe*21 + k]  (xe-major: <=2-way bank aliasing)
        const int mb = q * 4;
#pragma unroll
        for (int t2 = 0; t2 < 9; ++t2) {
            const int Xi = (t2 < 3) ? 0 : (t2 < 6 ? 1 : 2);
            constexpr int UJ[9] = {0, 1, 2, 1, 2, 3, 2, 3, 4};
            const int ub = UJ[t2] * 16;
#pragma unroll
            for (int rr = 0; rr < 4; ++rr) {
                const int xe = Xi * 16 + mb + rr;
                const int k  = ub + n - xe;
                if ((unsigned)k < 21u)
                    sc[xe * 21 + k] = acc[t2][rr];
            }
        }

        // wave-private store: gather 16 values first (breaks read->store chain),
        // then 16 stores. k-major for x-locality; stride-2, par sibling (in the
        // other par block) fills the other half of each line through L2.
        const size_t obase = ((size_t)(b * 441 + dyp * 21) * 64 + y) * 96 + par;
        float vals[16];
#pragma unroll
        for (int it = 0; it < 16; ++it) {
            const int e = it * 64 + lane;        // [0,1024), valid < 1008
            vals[it] = (e < 1008) ? sc[(e % 48) * 21 + (e / 48)] : 0.0f;
        }
#pragma unroll
        for (int it = 0; it < 16; ++it) {
            const int e = it * 64 + lane;
            if (e < 1008) {
                const int k  = e / 48;
                const int xe = e - k * 48;
                out[obase + (size_t)k * 6144 + 2 * xe] = vals[it] * (1.0f / 256.0f);
            }
        }
    }
}

extern "C" void kernel_launch(void* const* d_in, const int* in_sizes, int n_in,
                              void* d_out, int out_size, void* d_ws, size_t ws_size,
                              hipStream_t stream) {
    const float* in1 = (const float*)d_in[0];
    const float* in2 = (const float*)d_in[1];
    float* out = (float*)d_out;

    short* Ag = (short*)d_ws;                    // 256 planes * 24576 shorts = 12.58 MB
    short* Bg = Ag + (size_t)256 * PLANE;        // 12.58 MB

    corr_prepass<<<dim3(512), dim3(512), 0, stream>>>(in1, in2, Ag, Bg);
    corr_mfma<<<dim3(512), dim3(512), 0, stream>>>(Ag, Bg, out);
}